// Round 6
// baseline (378.924 us; speedup 1.0000x reference)
//
#include <hip/hip_runtime.h>
#include <math.h>

// Problem constants (B=8, C=512, H=W=64)
constexpr int CB = 8;
constexpr int CC = 512;
constexpr int CN = 4096;   // H*W
constexpr int CM = 1024;   // pooled positions
constexpr int C8 = 64;     // C/8
constexpr int C2 = 256;    // C/2

typedef __attribute__((ext_vector_type(8))) short short8;
typedef __attribute__((ext_vector_type(8))) _Float16 half8;
typedef __attribute__((ext_vector_type(4))) float f32x4;

__device__ inline unsigned short f2bf(float f) {
  unsigned int u = __float_as_uint(f);
  return (unsigned short)((u + 0x7FFFu + ((u >> 16) & 1u)) >> 16);
}
__device__ inline unsigned short f16bits(float f) {
  union { _Float16 h; unsigned short u; } c;
  c.h = (_Float16)f;
  return c.u;
}
// pack two positive floats to bf16 pair (round-half-up): lo=e0, hi=e1
__device__ inline unsigned int pk_bf(float e0, float e1) {
  return __builtin_amdgcn_perm(__float_as_uint(e1) + 0x8000u,
                               __float_as_uint(e0) + 0x8000u, 0x07060302u);
}

// ---------------------------------------------------------------------------
// Weight conversion: theta/phi -> f16 hi/lo (2-term), g -> f16, o -> bf16.
// ---------------------------------------------------------------------------
__global__ __launch_bounds__(256)
void conv_w(const float* __restrict__ wt, const float* __restrict__ wp,
            const float* __restrict__ wg, const float* __restrict__ wo,
            _Float16* __restrict__ wth, _Float16* __restrict__ wtl,
            _Float16* __restrict__ wph, _Float16* __restrict__ wpl,
            _Float16* __restrict__ wgf, unsigned short* __restrict__ woh) {
  const int i = blockIdx.x * 256 + threadIdx.x;
  if (i < 32768) {
    float a = wt[i];
    _Float16 h = (_Float16)a;
    wth[i] = h; wtl[i] = (_Float16)(a - (float)h);
    a = wp[i];
    h = (_Float16)a;
    wph[i] = h; wpl[i] = (_Float16)(a - (float)h);
  }
  wgf[i] = (_Float16)wg[i];
  woh[i] = f2bf(wo[i]);
}

// ---------------------------------------------------------------------------
// Transpose+convert: x fp32 [b][c][n] -> xT f16 [b][n][c].
// grid (64 n-tiles, 8 c-tiles, 8 b), 64x64 tiles.
// ---------------------------------------------------------------------------
__global__ __launch_bounds__(256)
void xpose(const float* __restrict__ X, _Float16* __restrict__ xT) {
  __shared__ __align__(16) float raw[64][68];
  const int b = blockIdx.z, c0 = blockIdx.y * 64, n0 = blockIdx.x * 64;
  const float* Xb = X + ((size_t)b * CC + c0) * CN + n0;
  const int tid = threadIdx.x;
#pragma unroll
  for (int it = 0; it < 4; ++it) {
    const int idx = it * 256 + tid;
    const int row = idx >> 4, col4 = (idx & 15) * 4;
    *(float4*)&raw[row][col4] = *(const float4*)&Xb[(size_t)row * CN + col4];
  }
  __syncthreads();
  unsigned short* Yb = (unsigned short*)(xT + ((size_t)b * CN + n0) * CC + c0);
#pragma unroll
  for (int it = 0; it < 4; ++it) {
    const int idx = it * 256 + tid;
    const int n = idx >> 4, c4 = (idx & 15) * 4;
    ushort4 o;
    o.x = f16bits(raw[c4 + 0][n]);
    o.y = f16bits(raw[c4 + 1][n]);
    o.z = f16bits(raw[c4 + 2][n]);
    o.w = f16bits(raw[c4 + 3][n]);
    *(ushort4*)&Yb[(size_t)n * CC + c4] = o;
  }
}

// ---------------------------------------------------------------------------
// theta projection (streaming f16 MFMA, 2-term W hi/lo), output transposed
// thT[b][pos][64] f16 via LDS transpose epilogue. grid (64, 8).
// ---------------------------------------------------------------------------
__global__ __launch_bounds__(256)
void proj_th(const _Float16* __restrict__ Wh, const _Float16* __restrict__ Wl,
             const _Float16* __restrict__ xT, _Float16* __restrict__ thT) {
  __shared__ __align__(16) unsigned short LT[64][68];
  const int b = blockIdx.y, n0 = blockIdx.x * 64;
  const int tid = threadIdx.x;
  const int w = tid >> 6, l = tid & 63;
  const int l15 = l & 15, quad = l >> 4;
  f32x4 acc[4] = {};
  const _Float16* Brow = xT + (size_t)(b * CN + n0 + w * 16 + l15) * CC;
  for (int k0 = 0; k0 < CC; k0 += 32) {
    const half8 bfr = *(const half8*)&Brow[k0 + quad * 8];
#pragma unroll
    for (int i = 0; i < 4; ++i) {
      const half8 ah = *(const half8*)&Wh[(size_t)(i * 16 + l15) * CC + k0 + quad * 8];
      const half8 al = *(const half8*)&Wl[(size_t)(i * 16 + l15) * CC + k0 + quad * 8];
      acc[i] = __builtin_amdgcn_mfma_f32_16x16x32_f16(ah, bfr, acc[i], 0, 0, 0);
      acc[i] = __builtin_amdgcn_mfma_f32_16x16x32_f16(al, bfr, acc[i], 0, 0, 0);
    }
  }
#pragma unroll
  for (int i = 0; i < 4; ++i)
#pragma unroll
    for (int r = 0; r < 4; ++r)
      LT[w * 16 + l15][i * 16 + quad * 4 + r] = f16bits(acc[i][r]);
  __syncthreads();
  unsigned short* Yb = (unsigned short*)(thT + (size_t)(b * CN + n0) * C8);
#pragma unroll
  for (int it = 0; it < 4; ++it) {
    const int idx = it * 256 + tid;
    const int pos = idx >> 4, c4 = (idx & 15) * 4;
    ushort4 v = *(const ushort4*)&LT[pos][c4];
    *(ushort4*)&Yb[(size_t)pos * C8 + c4] = v;
  }
}

// ---------------------------------------------------------------------------
// phi + g projections with FUSED 2x2 maxpool epilogue.
// mt=0: phi (2-term) -> phT[b][m][64] f16; mt=1..4: g -> gbf[b][c2][m] bf16.
// Wave w = image row tile*4+w. shfl_xor(1) horizontal; LDS row-pair combine.
// grid (16, 5, 8).
// ---------------------------------------------------------------------------
__global__ __launch_bounds__(256)
void proj_pg(const _Float16* __restrict__ Wph, const _Float16* __restrict__ Wpl,
             const _Float16* __restrict__ Wg, const _Float16* __restrict__ xT,
             _Float16* __restrict__ phT, unsigned short* __restrict__ gbf) {
  __shared__ float Pbuf[2][64][33];
  const int b = blockIdx.z, mt = blockIdx.y, tile = blockIdx.x;
  const int n0 = tile * 256;
  const int tid = threadIdx.x;
  const int w = tid >> 6, l = tid & 63;
  const int l15 = l & 15, quad = l >> 4;
  const bool isphi = (mt == 0);
  const _Float16* Ah = isphi ? Wph : (Wg + (size_t)(mt - 1) * 64 * CC);
  f32x4 acc[4][4] = {};
  const _Float16* Bbase = xT + (size_t)(b * CN + n0 + w * 64) * CC;
  for (int k0 = 0; k0 < CC; k0 += 32) {
    half8 bf[4], ah[4];
#pragma unroll
    for (int j = 0; j < 4; ++j)
      bf[j] = *(const half8*)&Bbase[(size_t)(j * 16 + l15) * CC + k0 + quad * 8];
#pragma unroll
    for (int i = 0; i < 4; ++i)
      ah[i] = *(const half8*)&Ah[(size_t)(i * 16 + l15) * CC + k0 + quad * 8];
#pragma unroll
    for (int i = 0; i < 4; ++i)
#pragma unroll
      for (int j = 0; j < 4; ++j)
        acc[i][j] = __builtin_amdgcn_mfma_f32_16x16x32_f16(ah[i], bf[j], acc[i][j], 0, 0, 0);
    if (isphi) {
      half8 al[4];
#pragma unroll
      for (int i = 0; i < 4; ++i)
        al[i] = *(const half8*)&Wpl[(size_t)(i * 16 + l15) * CC + k0 + quad * 8];
#pragma unroll
      for (int i = 0; i < 4; ++i)
#pragma unroll
        for (int j = 0; j < 4; ++j)
          acc[i][j] = __builtin_amdgcn_mfma_f32_16x16x32_f16(al[i], bf[j], acc[i][j], 0, 0, 0);
    }
  }
  // ---- pooled epilogue ----
  const bool owner = ((l15 & 1) == 0);
  const int colh = l15 >> 1;
  if (w & 1) {
#pragma unroll
    for (int i = 0; i < 4; ++i)
#pragma unroll
      for (int j = 0; j < 4; ++j)
#pragma unroll
        for (int r = 0; r < 4; ++r) {
          float v = acc[i][j][r];
          float o = __shfl_xor(v, 1);
          v = fmaxf(v, o);
          if (owner) Pbuf[w >> 1][i * 16 + quad * 4 + r][j * 8 + colh] = v;
        }
  }
  __syncthreads();
  if (!(w & 1)) {
    const int pr = tile * 2 + (w >> 1);
    unsigned short* phB = (unsigned short*)(phT + ((size_t)b * CM + pr * 32) * C8);
#pragma unroll
    for (int i = 0; i < 4; ++i)
#pragma unroll
      for (int j = 0; j < 4; ++j)
#pragma unroll
        for (int r = 0; r < 4; ++r) {
          float v = acc[i][j][r];
          float o = __shfl_xor(v, 1);
          v = fmaxf(v, o);
          if (owner) {
            const int oc = i * 16 + quad * 4 + r;
            const int col = j * 8 + colh;
            v = fmaxf(v, Pbuf[w >> 1][oc][col]);
            if (isphi)
              phB[(size_t)col * C8 + oc] = f16bits(v);
            else
              gbf[((size_t)b * C2 + (mt - 1) * 64 + oc) * CM + pr * 32 + col] = f2bf(v);
          }
        }
  }
}

// ---------------------------------------------------------------------------
// Fused attention v4 — no barriers, 32 queries/block for 2x occupancy.
// 4 waves split c2 (64 cols each); each wave computes S^T (2 qs) redundantly,
// exp, perm-packs to bf16, per-wave LDS round-trip into PV A-layout, PV mfma.
// grid (128, 8) = 1024 blocks -> 4 blocks/CU.
// ---------------------------------------------------------------------------
__global__ __launch_bounds__(256)
void attn_v4(const _Float16* __restrict__ thT, const _Float16* __restrict__ phT,
             const unsigned short* __restrict__ gbf,
             unsigned short* __restrict__ attbf) {
  __shared__ __align__(16) unsigned short Pl[4][2][16][40]; // [wave][qs][q][j+pad]
  const int b = blockIdx.y;
  const int q0 = blockIdx.x * 32;
  const int tid = threadIdx.x;
  const int w = tid >> 6, l = tid & 63;
  const int l15 = l & 15, quad = l >> 4;
  // theta B-frags (resident): 2 q-subtiles x 2 K-chunks
  half8 tb[2][2];
#pragma unroll
  for (int qs = 0; qs < 2; ++qs)
#pragma unroll
    for (int kc = 0; kc < 2; ++kc)
      tb[qs][kc] = *(const half8*)&thT[(size_t)(b * CN + q0 + qs * 16 + l15) * C8 +
                                       kc * 32 + quad * 8];
  f32x4 acc[2][4] = {};   // [qs][ct], wave's c2 = w*64 + ct*16 + l15
  float dnp[2] = {0.f, 0.f};
  const _Float16* phB = phT + (size_t)b * CM * C8;
  const unsigned short* gB = gbf + (size_t)b * C2 * CM;

  for (int j0 = 0; j0 < CM; j0 += 32) {
    half8 pa[2][2];
#pragma unroll
    for (int jt = 0; jt < 2; ++jt)
#pragma unroll
      for (int kc = 0; kc < 2; ++kc)
        pa[jt][kc] = *(const half8*)&phB[(size_t)(j0 + jt * 16 + l15) * C8 +
                                         kc * 32 + quad * 8];
    // S^T, exp, write in PV-A layout: thread (l15=q, quad) holds
    // j = jt*16 + quad*4 + r  ->  Pl[w][qs][l15][jt*16 + quad*4 .. +3]
#pragma unroll
    for (int qs = 0; qs < 2; ++qs) {
      f32x4 S0 = {0.f, 0.f, 0.f, 0.f}, S1 = {0.f, 0.f, 0.f, 0.f};
      S0 = __builtin_amdgcn_mfma_f32_16x16x32_f16(pa[0][0], tb[qs][0], S0, 0, 0, 0);
      S0 = __builtin_amdgcn_mfma_f32_16x16x32_f16(pa[0][1], tb[qs][1], S0, 0, 0, 0);
      S1 = __builtin_amdgcn_mfma_f32_16x16x32_f16(pa[1][0], tb[qs][0], S1, 0, 0, 0);
      S1 = __builtin_amdgcn_mfma_f32_16x16x32_f16(pa[1][1], tb[qs][1], S1, 0, 0, 0);
      float e0[4], e1[4];
#pragma unroll
      for (int r = 0; r < 4; ++r) { e0[r] = __expf(S0[r]); e1[r] = __expf(S1[r]); }
      dnp[qs] += (e0[0] + e0[1]) + (e0[2] + e0[3]) +
                 (e1[0] + e1[1]) + (e1[2] + e1[3]);
      uint2 v0, v1;
      v0.x = pk_bf(e0[0], e0[1]); v0.y = pk_bf(e0[2], e0[3]);
      v1.x = pk_bf(e1[0], e1[1]); v1.y = pk_bf(e1[2], e1[3]);
      *(uint2*)&Pl[w][qs][l15][quad * 4] = v0;
      *(uint2*)&Pl[w][qs][l15][16 + quad * 4] = v1;
    }
    // read back PV A-frags (A[m=l15][k=quad*8..+7]) — wave-local, no barrier
    short8 pfrag[2];
#pragma unroll
    for (int qs = 0; qs < 2; ++qs)
      pfrag[qs] = *(const short8*)&Pl[w][qs][l15][quad * 8];
#pragma unroll
    for (int ct = 0; ct < 4; ++ct) {
      const short8 gf = *(const short8*)&gB[(size_t)(w * 64 + ct * 16 + l15) * CM +
                                            j0 + quad * 8];
#pragma unroll
      for (int qs = 0; qs < 2; ++qs)
        acc[qs][ct] = __builtin_amdgcn_mfma_f32_16x16x32_bf16(pfrag[qs], gf,
                                                              acc[qs][ct], 0, 0, 0);
    }
  }
  // denominators + store
  unsigned short* attB = attbf + (size_t)(b * CN + q0) * C2;
#pragma unroll
  for (int qs = 0; qs < 2; ++qs) {
    float d = dnp[qs];
    d += __shfl_xor(d, 16);
    d += __shfl_xor(d, 32);
    const float inv = 1.0f / d;        // valid for q = l15 (all lanes)
#pragma unroll
    for (int r = 0; r < 4; ++r) {
      const float iv = __shfl(inv, quad * 4 + r);
      const int row = qs * 16 + quad * 4 + r;
#pragma unroll
      for (int ct = 0; ct < 4; ++ct)
        attB[(size_t)row * C2 + w * 64 + ct * 16 + l15] =
            f2bf(acc[qs][ct][r] * iv);
    }
  }
}

// ---------------------------------------------------------------------------
// Output projection v2: out = x + gamma * (Wo @ att), LDS-transpose epilogue
// for fully-coalesced float4 X-read / out-write. Grid (16, 8, 8).
// ---------------------------------------------------------------------------
__global__ __launch_bounds__(256)
void oproj_mfma(const unsigned short* __restrict__ woh,
                const unsigned short* __restrict__ attbf,
                const float* __restrict__ X, const float* __restrict__ gamma,
                float* __restrict__ out) {
  __shared__ __align__(16) float Ls[16][260];
  const int b = blockIdx.z;
  const int mt = blockIdx.y;
  const int n0 = blockIdx.x * 256;
  const int tid = threadIdx.x;
  const int w = tid >> 6, l = tid & 63;
  const int l15 = l & 15, quad = l >> 4;
  const unsigned short* Bb = attbf + (size_t)b * CN * C2;
  f32x4 acc[4][4] = {};
  for (int k0 = 0; k0 < C2; k0 += 32) {
    short8 a[4], bb[4];
#pragma unroll
    for (int i = 0; i < 4; ++i)
      a[i] = *(const short8*)&woh[(size_t)(mt * 64 + i * 16 + l15) * C2 + k0 + quad * 8];
#pragma unroll
    for (int j = 0; j < 4; ++j)
      bb[j] = *(const short8*)&Bb[(size_t)(n0 + w * 64 + j * 16 + l15) * C2 + k0 + quad * 8];
#pragma unroll
    for (int i = 0; i < 4; ++i)
#pragma unroll
      for (int j = 0; j < 4; ++j)
        acc[i][j] = __builtin_amdgcn_mfma_f32_16x16x32_bf16(a[i], bb[j], acc[i][j], 0, 0, 0);
  }
  const float gm = gamma[0];
  const int tr = tid >> 4;         // 0..15 (wave w covers rows w*4..w*4+3)
  const int cl = (tid & 15) * 4;   // 0..60
  for (int i = 0; i < 4; ++i) {
    __syncthreads();   // previous iteration's reads complete
#pragma unroll
    for (int j = 0; j < 4; ++j)
#pragma unroll
      for (int r = 0; r < 4; ++r)
        Ls[quad * 4 + r][w * 64 + j * 16 + l15] = acc[i][j][r];
    __syncthreads();
    const size_t row = (size_t)b * CC + mt * 64 + i * 16 + tr;
    const float* Xr = X + row * CN + n0;
    float* Or = out + row * CN + n0;
#pragma unroll
    for (int k = 0; k < 4; ++k) {
      const int col = k * 64 + cl;
      const float4 xv = *(const float4*)&Xr[col];
      const float4 lv = *(const float4*)&Ls[tr][col];
      float4 o = {xv.x + gm * lv.x, xv.y + gm * lv.y,
                  xv.z + gm * lv.z, xv.w + gm * lv.w};
      *(float4*)&Or[col] = o;
    }
  }
}

// ---------------------------------------------------------------------------
extern "C" void kernel_launch(void* const* d_in, const int* in_sizes, int n_in,
                              void* d_out, int out_size, void* d_ws, size_t ws_size,
                              hipStream_t stream) {
  const float* x       = (const float*)d_in[0];
  const float* w_theta = (const float*)d_in[1];
  const float* w_phi   = (const float*)d_in[2];
  const float* w_g     = (const float*)d_in[3];
  const float* w_o     = (const float*)d_in[4];
  const float* gamma   = (const float*)d_in[5];
  float* out = (float*)d_out;
  char* wsb = (char*)d_ws;

  // Workspace layout (bytes), total 43,778,048:
  _Float16*       xT    = (_Float16*)(wsb + 0);          // 32 MiB [B,4096,512]
  _Float16*       thT   = (_Float16*)(wsb + 33554432);   //  4 MiB [B,4096,64]
  _Float16*       phT   = (_Float16*)(wsb + 37748736);   //  1 MiB [B,1024,64]
  unsigned short* gbf   = (unsigned short*)(wsb + 38797312); // 4 MiB [B,256,1024]
  _Float16*       wth   = (_Float16*)(wsb + 42991616);
  _Float16*       wtl   = (_Float16*)(wsb + 43057152);
  _Float16*       wph   = (_Float16*)(wsb + 43122688);
  _Float16*       wpl   = (_Float16*)(wsb + 43188224);
  _Float16*       wgf   = (_Float16*)(wsb + 43253760);
  unsigned short* woh   = (unsigned short*)(wsb + 43515904);
  unsigned short* attbf = (unsigned short*)(wsb + 0);    // 16 MiB, aliases xT (dead)

  dim3 blk(256);
  conv_w<<<512, blk, 0, stream>>>(w_theta, w_phi, w_g, w_o,
                                  wth, wtl, wph, wpl, wgf, woh);
  xpose<<<dim3(64, 8, CB), blk, 0, stream>>>(x, xT);
  proj_th<<<dim3(64, CB), blk, 0, stream>>>(wth, wtl, xT, thT);
  proj_pg<<<dim3(16, 5, CB), blk, 0, stream>>>(wph, wpl, wgf, xT, phT, gbf);
  attn_v4<<<dim3(128, CB), blk, 0, stream>>>(thT, phT, gbf, attbf);
  oproj_mfma<<<dim3(16, 8, CB), blk, 0, stream>>>(woh, attbf, x, gamma, out);
}